// Round 1
// baseline (5153.649 us; speedup 1.0000x reference)
//
#include <hip/hip_runtime.h>
#include <hip/hip_bf16.h>
#include <cstdint>
#include <cstddef>

#define B_ 32
#define C_ 256
#define S_ 1024
#define L_ 8

static __device__ __forceinline__ float sigmoidf_(float x) {
    return 1.0f / (1.0f + __expf(-x));
}

// xs[b*1024 + s] = image[b, 0, (s/32)*16, (s%32)*16]
__global__ void make_xs_k(const float* __restrict__ img, float* __restrict__ xs) {
    int t = blockIdx.x * 256 + threadIdx.x;
    if (t >= B_ * S_) return;
    int b = t >> 10, s = t & 1023, i = s >> 5, k = s & 31;
    xs[t] = img[(size_t)b * 512 * 512 + (size_t)(i * 16) * 512 + k * 16];
}

// fw[c] = sum_o conv_w[o]*feat_w[o,c]; fb[c] = sum_o conv_b[o]*feat_w[o,c] + feat_b[c]
__global__ void fuse_wb_k(const float* __restrict__ cw, const float* __restrict__ cb,
                          const float* __restrict__ fwm, const float* __restrict__ fbv,
                          float* __restrict__ fw, float* __restrict__ fb) {
    int c = threadIdx.x;
    float a = 0.f, bs = 0.f;
    for (int o = 0; o < C_; o++) {
        float f = fwm[o * C_ + c];
        a += cw[o] * f;
        bs += cb[o] * f;
    }
    fw[c] = a;
    fb[c] = bs + fbv[c];
}

// X[b][c][s] = tanh(xs[b,s]*fw[c] + fb[c])   (B,C,S layout)
__global__ __launch_bounds__(256) void embed_k(const float* __restrict__ xs,
                                               const float* __restrict__ fw,
                                               const float* __restrict__ fb,
                                               float* __restrict__ X) {
    size_t t = (size_t)blockIdx.x * 256 + threadIdx.x;
    int n = (int)(t & 1023);
    int c = (int)((t >> 10) & 255);
    int b = (int)(t >> 18);
    X[t] = tanhf(xs[b * 1024 + n] * fw[c] + fb[c]);
}

// LayerNorm over channel dim; X,out in (B,C,S). thread per (b,s).
__global__ __launch_bounds__(256) void ln_k(const float* __restrict__ X,
                                            const float* __restrict__ g,
                                            const float* __restrict__ be,
                                            float* __restrict__ out) {
    int t = blockIdx.x * 256 + threadIdx.x;  // 0..32767
    int b = t >> 10, n = t & 1023;
    size_t base = (size_t)b * C_ * S_ + n;
    float sum = 0.f, sq = 0.f;
    for (int c = 0; c < C_; c++) {
        float v = X[base + (size_t)c * S_];
        sum += v;
        sq += v * v;
    }
    float mu = sum * (1.f / C_);
    float var = sq * (1.f / C_) - mu * mu;
    float rs = rsqrtf(var + 1e-5f);
    for (int c = 0; c < C_; c++) {
        float v = X[base + (size_t)c * S_];
        out[base + (size_t)c * S_] = (v - mu) * rs * g[c] + be[c];
    }
}

// out[b][m][n] = epilogue( sum_k W[k*wld + m*cmul + coff] * Xin[b][k][n] + bias[m*cmul+coff] )
// ACT: 0 none, 1 sigmoid, 2 relu. GATE: out = g0*ta + act(v). RES: out = act(v) + ta.
// M fixed 256, N fixed 1024, K fixed 256. grid (16, 4, B), block 256.
template <int ACT, bool GATE, bool RES>
__global__ __launch_bounds__(256) void gemm_k(const float* __restrict__ Xin,
                                              const float* __restrict__ W,
                                              const float* __restrict__ bias,
                                              float* __restrict__ out,
                                              const float* __restrict__ g0,
                                              const float* __restrict__ ta,
                                              int wld, int cmul, int coff) {
    __shared__ float Ws[16][64];
    __shared__ float Xs[16][64];
    int t = threadIdx.x;
    int n0 = blockIdx.x * 64, m0 = blockIdx.y * 64, b = blockIdx.z;
    const float* Xb = Xin + (size_t)b * C_ * S_;
    float acc[4][4] = {};
    int kk = t >> 4, q = t & 15;
    int ty = t >> 4, tx = t & 15;
    for (int k0 = 0; k0 < C_; k0 += 16) {
        if (cmul == 1) {
            *(float4*)&Ws[kk][q * 4] = *(const float4*)&W[(size_t)(k0 + kk) * wld + m0 + q * 4];
        } else {  // cmul == 2 (wa interleaved columns)
            const float* wp = &W[(size_t)(k0 + kk) * wld + (size_t)(m0 + q * 4) * 2 + coff];
            Ws[kk][q * 4 + 0] = wp[0];
            Ws[kk][q * 4 + 1] = wp[2];
            Ws[kk][q * 4 + 2] = wp[4];
            Ws[kk][q * 4 + 3] = wp[6];
        }
        *(float4*)&Xs[kk][q * 4] = *(const float4*)&Xb[(size_t)(k0 + kk) * S_ + n0 + q * 4];
        __syncthreads();
#pragma unroll
        for (int k = 0; k < 16; k++) {
            float4 av = *(float4*)&Ws[k][ty * 4];
            float4 bv = *(float4*)&Xs[k][tx * 4];
            float aa[4] = {av.x, av.y, av.z, av.w};
            float bb[4] = {bv.x, bv.y, bv.z, bv.w};
#pragma unroll
            for (int i = 0; i < 4; i++)
#pragma unroll
                for (int j = 0; j < 4; j++) acc[i][j] += aa[i] * bb[j];
        }
        __syncthreads();
    }
    size_t ob = (size_t)b * C_ * S_;
#pragma unroll
    for (int i = 0; i < 4; i++) {
        int m = m0 + ty * 4 + i;
        float bi = bias[m * cmul + coff];
#pragma unroll
        for (int j = 0; j < 4; j++) {
            int n = n0 + tx * 4 + j;
            size_t idx = ob + (size_t)m * S_ + n;
            float v = acc[i][j] + bi;
            if constexpr (ACT == 1) v = sigmoidf_(v);
            if constexpr (ACT == 2) v = fmaxf(v, 0.f);
            if constexpr (GATE) v = g0[idx] * ta[idx] + v;
            if constexpr (RES) v = v + ta[idx];
            out[idx] = v;
        }
    }
}

// Per (b,c) tiny attention; one wave per channel, 2 waves/block.
// Reads Q,K,V (B,C,S); X updated in place: X = x + attn_out  (becomes ta).
__global__ __launch_bounds__(128) void attn_k(const float* __restrict__ Q,
                                              const float* __restrict__ K,
                                              const float* __restrict__ V,
                                              float* __restrict__ X) {
    __shared__ float Qs[2][1024], Ks[2][1024], Vs[2][1024];
    __shared__ float qp[2][256], kp[2][256], s1[2][256], s2[2][256], kqv[2][256];
    const int w = threadIdx.x >> 6, lane = threadIdx.x & 63;
    const int gw = blockIdx.x * 2 + w;
    const int b = gw >> 8, c = gw & 255;
    const size_t base = ((size_t)b * C_ + c) * S_;
    for (int t = lane; t < 1024; t += 64) {
        Qs[w][t] = Q[base + t];
        Ks[w][t] = K[base + t];
        Vs[w][t] = V[base + t];
    }
    __syncthreads();
    // pooled qp,kp: [i2 in 8][k in 32], mean over 4 spatial rows
#pragma unroll
    for (int e = 0; e < 4; e++) {
        int idx = lane + 64 * e;
        int i2 = idx >> 5, k = idx & 31;
        int r = i2 * 128 + k;
        qp[w][idx] = 0.25f * (Qs[w][r] + Qs[w][r + 32] + Qs[w][r + 64] + Qs[w][r + 96]);
        kp[w][idx] = 0.25f * (Ks[w][r] + Ks[w][r + 32] + Ks[w][r + 64] + Ks[w][r + 96]);
    }
    __syncthreads();
    const float dsc = 0.0625f;  // 1/sqrt(256)
    // s1[i(32)][j(8)] = d * <Q[i,:], kp[j,:]>
#pragma unroll
    for (int e = 0; e < 4; e++) {
        int idx = lane + 64 * e;
        int i = idx >> 3, j = idx & 7;
        float a = 0.f;
        for (int k = 0; k < 32; k++) a += Qs[w][i * 32 + k] * kp[w][j * 32 + k];
        s1[w][idx] = a * dsc;
    }
    // s2[i2(8)][j(32)] = d * <qp[i2,:], K[j,:]>
#pragma unroll
    for (int e = 0; e < 4; e++) {
        int idx = lane + 64 * e;
        int i2 = idx >> 5, j = idx & 31;
        float a = 0.f;
        for (int k = 0; k < 32; k++) a += qp[w][i2 * 32 + k] * Ks[w][j * 32 + k];
        s2[w][idx] = a * dsc;
    }
    __syncthreads();
    // softmax: s1 rows of 8 (32 rows), s2 rows of 32 (8 rows)
    if (lane < 32) {
        int r = lane * 8;
        float m = s1[w][r];
        for (int j = 1; j < 8; j++) m = fmaxf(m, s1[w][r + j]);
        float sum = 0.f, ex[8];
        for (int j = 0; j < 8; j++) {
            ex[j] = __expf(s1[w][r + j] - m);
            sum += ex[j];
        }
        float inv = 1.f / sum;
        for (int j = 0; j < 8; j++) s1[w][r + j] = ex[j] * inv;
    } else if (lane < 40) {
        int r = (lane - 32) * 32;
        float m = s2[w][r];
        for (int j = 1; j < 32; j++) m = fmaxf(m, s2[w][r + j]);
        float sum = 0.f;
        for (int j = 0; j < 32; j++) {
            float e2 = __expf(s2[w][r + j] - m);
            s2[w][r + j] = e2;
            sum += e2;
        }
        float inv = 1.f / sum;
        for (int j = 0; j < 32; j++) s2[w][r + j] *= inv;
    }
    __syncthreads();
    // kqv[i2(8)][j(32)] = sum_k s2[i2,k] * V[k,j]
#pragma unroll
    for (int e = 0; e < 4; e++) {
        int idx = lane + 64 * e;
        int i2 = idx >> 5, j = idx & 31;
        float a = 0.f;
        for (int k = 0; k < 32; k++) a += s2[w][i2 * 32 + k] * Vs[w][k * 32 + j];
        kqv[w][idx] = a;
    }
    __syncthreads();
    // out[i(32)][j(32)] = sum_k s1[i,k] * kqv[k,j]; X += out (ta = x + a)
    for (int t = lane; t < 1024; t += 64) {
        int i = t >> 5, j = t & 31;
        float a = 0.f;
#pragma unroll
        for (int k = 0; k < 8; k++) a += s1[w][i * 8 + k] * kqv[w][k * 32 + j];
        X[base + t] += a;
    }
}

// (B,C,S) -> (B,S,C) tiled transpose into an output slot
__global__ __launch_bounds__(256) void tr_k(const float* __restrict__ src, float* __restrict__ dst) {
    __shared__ float tile[32][33];
    int b = blockIdx.z, c0 = blockIdx.y * 32, s0 = blockIdx.x * 32;
    int tx = threadIdx.x, ty = threadIdx.y;  // (32,8)
#pragma unroll
    for (int r = 0; r < 4; r++)
        tile[ty + 8 * r][tx] = src[((size_t)b * C_ + c0 + ty + 8 * r) * S_ + s0 + tx];
    __syncthreads();
#pragma unroll
    for (int r = 0; r < 4; r++)
        dst[((size_t)b * S_ + s0 + ty + 8 * r) * C_ + c0 + tx] = tile[tx][ty + 8 * r];
}

extern "C" void kernel_launch(void* const* d_in, const int* in_sizes, int n_in,
                              void* d_out, int out_size, void* d_ws, size_t ws_size,
                              hipStream_t stream) {
    const float* image  = (const float*)d_in[0];
    const float* conv_w = (const float*)d_in[1];
    const float* conv_b = (const float*)d_in[2];
    const float* feat_w = (const float*)d_in[3];
    const float* feat_b = (const float*)d_in[4];
    const float* ln_s   = (const float*)d_in[5];
    const float* ln_b   = (const float*)d_in[6];
    const float* wq     = (const float*)d_in[7];
    const float* bq     = (const float*)d_in[8];
    const float* wk     = (const float*)d_in[9];
    const float* bk     = (const float*)d_in[10];
    const float* wv     = (const float*)d_in[11];
    const float* bv     = (const float*)d_in[12];
    const float* wf     = (const float*)d_in[13];
    const float* bf     = (const float*)d_in[14];
    const float* wa     = (const float*)d_in[15];
    const float* ba     = (const float*)d_in[16];
    float* out = (float*)d_out;

    char* ws = (char*)d_ws;
    const size_t MB32 = (size_t)B_ * C_ * S_ * sizeof(float);  // 33554432
    float* xs = (float*)ws;            // 32768 floats
    float* fw = xs + B_ * S_;          // 256
    float* fb = fw + C_;               // 256
    float* X  = (float*)(ws + (1u << 20));
    float* tn = (float*)(ws + (1u << 20) + 1 * MB32);
    float* Qb = (float*)(ws + (1u << 20) + 2 * MB32);
    float* Kb = (float*)(ws + (1u << 20) + 3 * MB32);
    float* Vb = (float*)(ws + (1u << 20) + 4 * MB32);
    // Fallback if workspace is short: V lives in out slot 0 (only written at the very end).
    if (ws_size < (1u << 20) + 5 * MB32) Vb = out;

    make_xs_k<<<128, 256, 0, stream>>>(image, xs);
    fuse_wb_k<<<1, 256, 0, stream>>>(conv_w, conv_b, feat_w, feat_b, fw, fb);
    embed_k<<<32768, 256, 0, stream>>>(xs, fw, fb, X);

    const dim3 gg(16, 4, 32);
    const dim3 tg(32, 8, 32), tb(32, 8);
    const size_t slot = (size_t)B_ * S_ * C_;

    for (int l = 0; l < L_; l++) {
        const float* wq_l = wq + (size_t)l * C_ * C_;
        const float* wk_l = wk + (size_t)l * C_ * C_;
        const float* wv_l = wv + (size_t)l * C_ * C_;
        const float* wf_l = wf + (size_t)l * C_ * C_;
        const float* wa_l = wa + (size_t)l * C_ * 2 * C_;
        const float* bq_l = bq + l * C_;
        const float* bk_l = bk + l * C_;
        const float* bv_l = bv + l * C_;
        const float* bf_l = bf + l * C_;
        const float* ba_l = ba + l * 2 * C_;

        ln_k<<<128, 256, 0, stream>>>(X, ln_s + l * C_, ln_b + l * C_, tn);
        gemm_k<1, false, false><<<gg, 256, 0, stream>>>(tn, wq_l, bq_l, Qb, nullptr, nullptr, 256, 1, 0);
        gemm_k<1, false, false><<<gg, 256, 0, stream>>>(tn, wk_l, bk_l, Kb, nullptr, nullptr, 256, 1, 0);
        gemm_k<1, false, false><<<gg, 256, 0, stream>>>(tn, wv_l, bv_l, Vb, nullptr, nullptr, 256, 1, 0);
        attn_k<<<4096, 128, 0, stream>>>(Qb, Kb, Vb, X);  // X becomes ta

        int snap = (l == 2) ? 0 : (l == 4) ? 1 : (l == 6) ? 2 : -1;
        if (snap >= 0) tr_k<<<tg, tb, 0, stream>>>(X, out + (size_t)(4 + snap) * slot);  // att

        // g0 = sigmoid(ta @ wa[:, even] + ba[even])  -> reuse Qb
        gemm_k<1, false, false><<<gg, 256, 0, stream>>>(X, wa_l, ba_l, Qb, nullptr, nullptr, 512, 2, 0);
        // tn2 = g0 * ta + sigmoid(ta @ wa[:, odd] + ba[odd]) -> tn
        gemm_k<1, true, false><<<gg, 256, 0, stream>>>(X, wa_l, ba_l, tn, Qb, X, 512, 2, 1);
        // x = relu(tn2 @ wf + bf) + ta  (in place into X)
        gemm_k<2, false, true><<<gg, 256, 0, stream>>>(tn, wf_l, bf_l, X, nullptr, X, 256, 1, 0);

        if (snap >= 0) tr_k<<<tg, tb, 0, stream>>>(X, out + (size_t)(1 + snap) * slot);  // hid
    }
    tr_k<<<tg, tb, 0, stream>>>(X, out);  // final x -> slot 0
}

// Round 2
// 1333.673 us; speedup vs baseline: 3.8643x; 3.8643x over previous
//
#include <hip/hip_runtime.h>
#include <hip/hip_bf16.h>
#include <cstdint>
#include <cstddef>

#define B_ 32
#define C_ 256
#define S_ 1024
#define L_ 8

typedef unsigned short bf16_t;
typedef __attribute__((ext_vector_type(8))) short s8v;   // 8 bf16 (16B)
typedef __attribute__((ext_vector_type(4))) short s4v;   // 4 bf16 (8B)
typedef __attribute__((ext_vector_type(4))) float f4v;

static __device__ __forceinline__ float b2f(bf16_t v) {
    unsigned int u = ((unsigned int)v) << 16;
    float f;
    __builtin_memcpy(&f, &u, 4);
    return f;
}
static __device__ __forceinline__ bf16_t f2b(float f) {
    unsigned int u;
    __builtin_memcpy(&u, &f, 4);
    u += 0x7fffu + ((u >> 16) & 1u);
    return (bf16_t)(u >> 16);
}
static __device__ __forceinline__ float sigmoidf_(float x) {
    return 1.0f / (1.0f + __expf(-x));
}
static __device__ __forceinline__ void gload_lds16(const void* g, void* l) {
    __builtin_amdgcn_global_load_lds((const __attribute__((address_space(1))) void*)g,
                                     (__attribute__((address_space(3))) void*)l, 16, 0, 0);
}

// ---------------- prologue kernels ----------------

// xs[b*1024 + s] = image[b, 0, (s/32)*16, (s%32)*16]
__global__ void make_xs_k(const float* __restrict__ img, float* __restrict__ xs) {
    int t = blockIdx.x * 256 + threadIdx.x;
    if (t >= B_ * S_) return;
    int b = t >> 10, s = t & 1023, i = s >> 5, k = s & 31;
    xs[t] = img[(size_t)b * 512 * 512 + (size_t)(i * 16) * 512 + k * 16];
}

// fw[c] = sum_o conv_w[o]*feat_w[o,c]; fb[c] = sum_o conv_b[o]*feat_w[o,c] + feat_b[c]
__global__ void fuse_wb_k(const float* __restrict__ cw, const float* __restrict__ cb,
                          const float* __restrict__ fwm, const float* __restrict__ fbv,
                          float* __restrict__ fw, float* __restrict__ fb) {
    int c = threadIdx.x;
    float a = 0.f, bs = 0.f;
    for (int o = 0; o < C_; o++) {
        float f = fwm[o * C_ + c];
        a += cw[o] * f;
        bs += cb[o] * f;
    }
    fw[c] = a;
    fb[c] = bs + fbv[c];
}

// Transposed bf16 weights: WT[(l*6+tp)][m][k] with tp: 0=q 1=k 2=v 3=f 4=wa_even 5=wa_odd
__global__ __launch_bounds__(256) void wtrans_k(const float* __restrict__ wq, const float* __restrict__ wk,
                                                const float* __restrict__ wv, const float* __restrict__ wf,
                                                const float* __restrict__ wa, bf16_t* __restrict__ WT) {
    __shared__ float t[32][33];
    int z = blockIdx.z, l = z / 6, tp = z - l * 6;
    const float* src;
    int ld, cmul, coff;
    if (tp < 4) {
        const float* bases[4] = {wq, wk, wv, wf};
        src = bases[tp] + (size_t)l * 65536;
        ld = 256; cmul = 1; coff = 0;
    } else {
        src = wa + (size_t)l * 131072;
        ld = 512; cmul = 2; coff = tp - 4;
    }
    bf16_t* dst = WT + ((size_t)l * 6 + tp) * 65536;
    int k0 = blockIdx.y * 32, m0 = blockIdx.x * 32;
    int tx = threadIdx.x & 31, ty = threadIdx.x >> 5;
#pragma unroll
    for (int r = 0; r < 4; ++r)
        t[ty + 8 * r][tx] = src[(size_t)(k0 + ty + 8 * r) * ld + (m0 + tx) * cmul + coff];
    __syncthreads();
#pragma unroll
    for (int r = 0; r < 4; ++r)
        dst[(size_t)(m0 + ty + 8 * r) * 256 + k0 + tx] = f2b(t[tx][ty + 8 * r]);
}

// X[b][s][c] = tanh(xs[b,s]*fw[c]+fb[c])  -- (B,S,C) bf16, wave per row
__global__ __launch_bounds__(256) void embed_k(const float* __restrict__ xs, const float* __restrict__ fw,
                                               const float* __restrict__ fb, bf16_t* __restrict__ X) {
    int wid = threadIdx.x >> 6, lane = threadIdx.x & 63;
    int row = blockIdx.x * 4 + wid;
    float xv = xs[row];
    f4v fwv = *(const f4v*)(fw + lane * 4);
    f4v fbv = *(const f4v*)(fb + lane * 4);
    s4v o;
#pragma unroll
    for (int j = 0; j < 4; ++j) o[j] = (short)f2b(tanhf(xv * fwv[j] + fbv[j]));
    *(s4v*)(X + (size_t)row * 256 + lane * 4) = o;
}

// LayerNorm over C (contiguous). wave per row.
__global__ __launch_bounds__(256) void ln_k(const bf16_t* __restrict__ X, const float* __restrict__ g,
                                            const float* __restrict__ be, bf16_t* __restrict__ tn) {
    int wid = threadIdx.x >> 6, lane = threadIdx.x & 63;
    int row = blockIdx.x * 4 + wid;
    s4v v = *(const s4v*)(X + (size_t)row * 256 + lane * 4);
    float f[4], sum = 0.f, sq = 0.f;
#pragma unroll
    for (int j = 0; j < 4; ++j) {
        f[j] = b2f((bf16_t)v[j]);
        sum += f[j];
        sq += f[j] * f[j];
    }
#pragma unroll
    for (int off = 32; off > 0; off >>= 1) {
        sum += __shfl_xor(sum, off);
        sq += __shfl_xor(sq, off);
    }
    float mu = sum * (1.f / 256.f);
    float var = sq * (1.f / 256.f) - mu * mu;
    float rs = rsqrtf(var + 1e-5f);
    f4v gv = *(const f4v*)(g + lane * 4);
    f4v bv = *(const f4v*)(be + lane * 4);
    s4v o;
#pragma unroll
    for (int j = 0; j < 4; ++j) o[j] = (short)f2b((f[j] - mu) * rs * gv[j] + bv[j]);
    *(s4v*)(tn + (size_t)row * 256 + lane * 4) = o;
}

// ---------------- MFMA GEMM ----------------
// out[s][m] = epi( sum_k A[s][k] * Wt[m][k] ),  A (B,S,C) bf16, Wt [M][256] bf16.
// MODE 0: QKV stacked (M=768), sigmoid, LDS-transpose epilogue -> (B,C,S) outputs O0/O1/O2
// MODE 1: gate dual: tn2 = sig(acc0+ba[2m])*ta + sig(acc1+ba[2m+1]) -> O0 (B,S,C)
// MODE 2: wf: x = relu(acc+bf)+ta -> O0 (B,S,C), optional fp32 hid
template <int MODE, bool HID>
__global__ __launch_bounds__(256) void mm_k(const bf16_t* Ain,
                                            const bf16_t* __restrict__ W0,
                                            const bf16_t* __restrict__ W1,
                                            const float* __restrict__ bias0,
                                            const float* __restrict__ bias1,
                                            const float* __restrict__ bias2,
                                            const bf16_t* ta,
                                            bf16_t* O0, bf16_t* O1, bf16_t* O2,
                                            float* __restrict__ hid) {
    __shared__ char lds[32768];
    char* XS = lds;             // [128 rows][128B]
    char* WS0 = lds + 16384;    // [64 rows][128B]
    char* WS1 = lds + 24576;    // MODE1 only
    const int tid = threadIdx.x, lane = tid & 63, wid = tid >> 6;
    const int wrow = wid >> 1, wcol = wid & 1;
    const int s0 = blockIdx.y * 128, mt0 = blockIdx.x * 64, b = blockIdx.z;

    const int lr8 = lane >> 3;            // row-in-8 for staging
    const int pbyte = (lane & 7) << 4;    // phys byte slot
    const int cb0 = pbyte ^ (lr8 << 4);   // logical col byte (swizzle pre-applied to source)

    const char* Ag = (const char*)Ain + (((size_t)b * 1024 + s0) * 256) * 2 + cb0;
    const char* Wg0 = (const char*)W0 + ((size_t)mt0 * 256) * 2 + cb0;
    const char* Wg1 = (const char*)W1 + ((size_t)mt0 * 256) * 2 + cb0;

    f4v acc[4][2] = {};
    f4v acc1[4][2] = {};

    for (int kt = 0; kt < 4; ++kt) {
        const char* ga = Ag + kt * 128;
#pragma unroll
        for (int q = 0; q < 4; ++q) {
            int r0 = wid * 32 + q * 8;
            gload_lds16(ga + (size_t)(r0 + lr8) * 512, XS + r0 * 128);
        }
        const char* gw = Wg0 + kt * 128;
#pragma unroll
        for (int p = 0; p < 2; ++p) {
            int r0 = wid * 16 + p * 8;
            gload_lds16(gw + (size_t)(r0 + lr8) * 512, WS0 + r0 * 128);
        }
        if constexpr (MODE == 1) {
            const char* gw1 = Wg1 + kt * 128;
#pragma unroll
            for (int p = 0; p < 2; ++p) {
                int r0 = wid * 16 + p * 8;
                gload_lds16(gw1 + (size_t)(r0 + lr8) * 512, WS1 + r0 * 128);
            }
        }
        __syncthreads();
#pragma unroll
        for (int kk = 0; kk < 2; ++kk) {
            const int cb = kk * 64 + ((lane >> 4) << 4);
            s8v av[4];
#pragma unroll
            for (int mi = 0; mi < 4; ++mi) {
                int r = wrow * 64 + mi * 16 + (lane & 15);
                av[mi] = *(const s8v*)(XS + r * 128 + (cb ^ ((r & 7) << 4)));
            }
            s8v bv[2], bw[2];
#pragma unroll
            for (int ni = 0; ni < 2; ++ni) {
                int m = wcol * 32 + ni * 16 + (lane & 15);
                bv[ni] = *(const s8v*)(WS0 + m * 128 + (cb ^ ((m & 7) << 4)));
                if constexpr (MODE == 1)
                    bw[ni] = *(const s8v*)(WS1 + m * 128 + (cb ^ ((m & 7) << 4)));
            }
#pragma unroll
            for (int mi = 0; mi < 4; ++mi)
#pragma unroll
                for (int ni = 0; ni < 2; ++ni) {
                    acc[mi][ni] = __builtin_amdgcn_mfma_f32_16x16x32_bf16(av[mi], bv[ni], acc[mi][ni], 0, 0, 0);
                    if constexpr (MODE == 1)
                        acc1[mi][ni] = __builtin_amdgcn_mfma_f32_16x16x32_bf16(av[mi], bw[ni], acc1[mi][ni], 0, 0, 0);
                }
        }
        __syncthreads();
    }

    if constexpr (MODE == 0) {
        const int mat = mt0 >> 8;
        const float* bs = (mat == 0) ? bias0 : (mat == 1 ? bias1 : bias2);
        bf16_t* Os = (mat == 0) ? O0 : (mat == 1 ? O1 : O2);
        const int mw = mt0 & 255;
        bf16_t* T = (bf16_t*)lds;  // [64][144]
#pragma unroll
        for (int mi = 0; mi < 4; ++mi)
#pragma unroll
            for (int ni = 0; ni < 2; ++ni) {
                int ml = wcol * 32 + ni * 16 + (lane & 15);
                float bi = bs[mw + ml];
#pragma unroll
                for (int r = 0; r < 4; ++r) {
                    int sl = wrow * 64 + mi * 16 + (lane >> 4) * 4 + r;
                    T[ml * 144 + sl] = f2b(sigmoidf_(acc[mi][ni][r] + bi));
                }
            }
        __syncthreads();
        int m = tid >> 2, c0 = (tid & 3) * 32;
        bf16_t* dst = Os + ((size_t)(b * 256 + mw + m)) * 1024 + s0 + c0;
#pragma unroll
        for (int j = 0; j < 4; ++j)
            *(s8v*)(dst + j * 8) = *(const s8v*)(T + m * 144 + c0 + j * 8);
    } else {
#pragma unroll
        for (int mi = 0; mi < 4; ++mi)
#pragma unroll
            for (int ni = 0; ni < 2; ++ni) {
                int ml = mt0 + wcol * 32 + ni * 16 + (lane & 15);
#pragma unroll
                for (int r = 0; r < 4; ++r) {
                    int sg = b * 1024 + s0 + wrow * 64 + mi * 16 + (lane >> 4) * 4 + r;
                    size_t idx = (size_t)sg * 256 + ml;
                    if constexpr (MODE == 1) {
                        float v = sigmoidf_(acc[mi][ni][r] + bias0[2 * ml]) * b2f(ta[idx]) +
                                  sigmoidf_(acc1[mi][ni][r] + bias0[2 * ml + 1]);
                        O0[idx] = f2b(v);
                    } else {
                        float v = fmaxf(acc[mi][ni][r] + bias0[ml], 0.f) + b2f(ta[idx]);
                        O0[idx] = f2b(v);
                        if constexpr (HID) hid[idx] = v;
                    }
                }
            }
    }
}

// ---------------- attention ----------------
// wave per (b,c); Q,K,V,A all (B,C,S) bf16. A = attention output (not accumulated).
__global__ __launch_bounds__(128) void attn_k(const bf16_t* __restrict__ Q, const bf16_t* __restrict__ K,
                                              const bf16_t* __restrict__ V, bf16_t* __restrict__ A) {
    __shared__ float L[2][4512];
    const int w = threadIdx.x >> 6, lane = threadIdx.x & 63;
    const int gw = blockIdx.x * 2 + w;
    const int b = gw >> 8, c = gw & 255;
    const size_t base = ((size_t)b * 256 + c) * 1024;
    float* Qs = L[w];          // [32][33]
    float* Ks = Qs + 1056;     // [32][33]
    float* Vs = Ks + 1056;     // [32][33]
    float* qp = Vs + 1056;     // [8][33]
    float* kp = qp + 264;      // [8][33]
    float* s1 = kp + 264;      // [32][9]
    float* s2 = s1 + 288;      // [8][33]
    float* kq = s2 + 264;      // [8][33]
#pragma unroll
    for (int h = 0; h < 2; ++h) {
        s8v vq = *((const s8v*)(Q + base) + lane * 2 + h);
        s8v vk = *((const s8v*)(K + base) + lane * 2 + h);
        s8v vv = *((const s8v*)(V + base) + lane * 2 + h);
#pragma unroll
        for (int j = 0; j < 8; ++j) {
            int e = lane * 16 + h * 8 + j;
            int ad = (e >> 5) * 33 + (e & 31);
            Qs[ad] = b2f((bf16_t)vq[j]);
            Ks[ad] = b2f((bf16_t)vk[j]);
            Vs[ad] = b2f((bf16_t)vv[j]);
        }
    }
    __syncthreads();
#pragma unroll
    for (int e = 0; e < 4; ++e) {
        int idx = lane + 64 * e;
        int i2 = idx >> 5, k = idx & 31;
        int r = i2 * 132 + k;
        qp[i2 * 33 + k] = 0.25f * (Qs[r] + Qs[r + 33] + Qs[r + 66] + Qs[r + 99]);
        kp[i2 * 33 + k] = 0.25f * (Ks[r] + Ks[r + 33] + Ks[r + 66] + Ks[r + 99]);
    }
    __syncthreads();
    const float dsc = 0.0625f;
#pragma unroll
    for (int e = 0; e < 4; ++e) {
        int idx = lane + 64 * e;
        int i = idx >> 3, j = idx & 7;
        float a = 0.f;
#pragma unroll
        for (int k = 0; k < 32; ++k) a += Qs[i * 33 + k] * kp[j * 33 + k];
        s1[i * 9 + j] = a * dsc;
    }
#pragma unroll
    for (int e = 0; e < 4; ++e) {
        int idx = lane + 64 * e;
        int i2 = idx >> 5, j = idx & 31;
        float a = 0.f;
#pragma unroll
        for (int k = 0; k < 32; ++k) a += qp[i2 * 33 + k] * Ks[j * 33 + k];
        s2[i2 * 33 + j] = a * dsc;
    }
    __syncthreads();
    if (lane < 32) {
        int r = lane * 9;
        float m = s1[r];
        for (int j = 1; j < 8; ++j) m = fmaxf(m, s1[r + j]);
        float sum = 0.f, ex[8];
        for (int j = 0; j < 8; ++j) {
            ex[j] = __expf(s1[r + j] - m);
            sum += ex[j];
        }
        float inv = 1.f / sum;
        for (int j = 0; j < 8; ++j) s1[r + j] = ex[j] * inv;
    } else if (lane < 40) {
        int r = (lane - 32) * 33;
        float m = s2[r];
        for (int j = 1; j < 32; ++j) m = fmaxf(m, s2[r + j]);
        float sum = 0.f;
        for (int j = 0; j < 32; ++j) {
            float e2 = __expf(s2[r + j] - m);
            s2[r + j] = e2;
            sum += e2;
        }
        float inv = 1.f / sum;
        for (int j = 0; j < 32; ++j) s2[r + j] *= inv;
    }
    __syncthreads();
#pragma unroll
    for (int e = 0; e < 4; ++e) {
        int idx = lane + 64 * e;
        int i2 = idx >> 5, j = idx & 31;
        float a = 0.f;
#pragma unroll
        for (int k = 0; k < 32; ++k) a += s2[i2 * 33 + k] * Vs[k * 33 + j];
        kq[i2 * 33 + j] = a;
    }
    __syncthreads();
    for (int t = lane; t < 1024; t += 64) {
        int i = t >> 5, j = t & 31;
        float a = 0.f;
#pragma unroll
        for (int k = 0; k < 8; ++k) a += s1[i * 9 + k] * kq[k * 33 + j];
        A[base + t] = f2b(a);
    }
}

// ta = X + A^T : A (B,C,S) -> add into X (B,S,C); optional fp32 att snapshot
template <bool SNAP>
__global__ __launch_bounds__(256) void add_tr_k(const bf16_t* __restrict__ Aa, bf16_t* X,
                                                float* __restrict__ att) {
    __shared__ float T[32][33];
    int b = blockIdx.z, c0 = blockIdx.y * 32, s0 = blockIdx.x * 32;
    int tx = threadIdx.x & 31, ty = threadIdx.x >> 5;
#pragma unroll
    for (int r = 0; r < 4; ++r)
        T[ty + 8 * r][tx] = b2f(Aa[((size_t)(b * 256 + c0 + ty + 8 * r)) * 1024 + s0 + tx]);
    __syncthreads();
#pragma unroll
    for (int r = 0; r < 4; ++r) {
        int s = s0 + ty + 8 * r;
        size_t idx = ((size_t)(b * 1024 + s)) * 256 + c0 + tx;
        float v = b2f(X[idx]) + T[tx][ty + 8 * r];
        X[idx] = f2b(v);
        if constexpr (SNAP) att[idx] = v;
    }
}

// ---------------- launch ----------------

extern "C" void kernel_launch(void* const* d_in, const int* in_sizes, int n_in,
                              void* d_out, int out_size, void* d_ws, size_t ws_size,
                              hipStream_t stream) {
    const float* image  = (const float*)d_in[0];
    const float* conv_w = (const float*)d_in[1];
    const float* conv_b = (const float*)d_in[2];
    const float* feat_w = (const float*)d_in[3];
    const float* feat_b = (const float*)d_in[4];
    const float* ln_s   = (const float*)d_in[5];
    const float* ln_b   = (const float*)d_in[6];
    const float* wq     = (const float*)d_in[7];
    const float* bq     = (const float*)d_in[8];
    const float* wk     = (const float*)d_in[9];
    const float* bk     = (const float*)d_in[10];
    const float* wv     = (const float*)d_in[11];
    const float* bv     = (const float*)d_in[12];
    const float* wf     = (const float*)d_in[13];
    const float* bfv    = (const float*)d_in[14];
    const float* wa     = (const float*)d_in[15];
    const float* ba     = (const float*)d_in[16];
    float* out = (float*)d_out;

    char* p = (char*)d_ws;
    const size_t MB16 = (size_t)B_ * S_ * C_ * sizeof(bf16_t);  // 16777216
    float* xs = (float*)p;                 p += 131072;
    float* fw = (float*)p;                 p += 1024;
    float* fb = (float*)p;                 p += 1024;
    bf16_t* WT = (bf16_t*)p;               p += (size_t)48 * 65536 * 2;
    bf16_t* X  = (bf16_t*)p;               p += MB16;
    bf16_t* T1 = (bf16_t*)p;               p += MB16;  // tn, then attn-delta
    bf16_t* T2 = (bf16_t*)p;               p += MB16;  // tn2
    bf16_t* Qb = (bf16_t*)p;               p += MB16;
    bf16_t* Kb = (bf16_t*)p;               p += MB16;
    bf16_t* Vb = (bf16_t*)p;               p += MB16;
    size_t needed = (size_t)(p - (char*)d_ws);
    if (ws_size < needed) Vb = (bf16_t*)d_out;  // out slot0 only written at the very end

    make_xs_k<<<128, 256, 0, stream>>>(image, xs);
    fuse_wb_k<<<1, 256, 0, stream>>>(conv_w, conv_b, feat_w, feat_b, fw, fb);
    wtrans_k<<<dim3(8, 8, 48), 256, 0, stream>>>(wq, wk, wv, wf, wa, WT);
    embed_k<<<8192, 256, 0, stream>>>(xs, fw, fb, X);

    const size_t slot = (size_t)B_ * S_ * C_;

    for (int l = 0; l < L_; ++l) {
        const bf16_t* WTl = WT + (size_t)l * 6 * 65536;
        int snap = (l == 2) ? 0 : (l == 4) ? 1 : (l == 6) ? 2 : -1;

        ln_k<<<8192, 256, 0, stream>>>(X, ln_s + l * 256, ln_b + l * 256, T1);
        mm_k<0, false><<<dim3(12, 8, 32), 256, 0, stream>>>(
            T1, WTl, nullptr, bq + l * 256, bk + l * 256, bv + l * 256, nullptr, Qb, Kb, Vb, nullptr);
        attn_k<<<4096, 128, 0, stream>>>(Qb, Kb, Vb, T1);
        if (snap >= 0)
            add_tr_k<true><<<dim3(32, 8, 32), 256, 0, stream>>>(T1, X, out + (size_t)(4 + snap) * slot);
        else
            add_tr_k<false><<<dim3(32, 8, 32), 256, 0, stream>>>(T1, X, nullptr);
        // X is now ta
        mm_k<1, false><<<dim3(4, 8, 32), 256, 0, stream>>>(
            X, WTl + 4 * 65536, WTl + 5 * 65536, ba + l * 512, nullptr, nullptr, X, T2, nullptr, nullptr, nullptr);
        float* hid = (snap >= 0) ? out + (size_t)(1 + snap) * slot : (l == 7 ? out : nullptr);
        if (hid)
            mm_k<2, true><<<dim3(4, 8, 32), 256, 0, stream>>>(
                T2, WTl + 3 * 65536, nullptr, bfv + l * 256, nullptr, nullptr, X, X, nullptr, nullptr, hid);
        else
            mm_k<2, false><<<dim3(4, 8, 32), 256, 0, stream>>>(
                T2, WTl + 3 * 65536, nullptr, bfv + l * 256, nullptr, nullptr, X, X, nullptr, nullptr, nullptr);
    }
}